// Round 1
// baseline (986.637 us; speedup 1.0000x reference)
//
#include <hip/hip_runtime.h>

#define NCH 128   // EMBED
#define NH  8     // HEADS
#define HID 512
#define SLOPE 0.2f
#define BN_EPS 1e-5f

__device__ inline void fma4(float4& acc, float a, const float4& w) {
  acc.x += a * w.x; acc.y += a * w.y; acc.z += a * w.z; acc.w += a * w.w;
}

// ---------------- zero fill ----------------
__global__ void fill_zero4(float* __restrict__ p, int n4) {
  int i = blockIdx.x * blockDim.x + threadIdx.x;
  if (i < n4) ((float4*)p)[i] = make_float4(0.f, 0.f, 0.f, 0.f);
}

// ---------------- feat = x @ W  (W 128x128 in LDS) ----------------
__global__ __launch_bounds__(256) void feat_gemm(const float* __restrict__ x,
                                                 const float* __restrict__ W,
                                                 float* __restrict__ feat, int N) {
  __shared__ float wl[128][128];    // 64 KB
  __shared__ float rowL[32][128];   // 16 KB
  int tid = threadIdx.x;
  int r0 = blockIdx.x * 32;
  for (int i = tid; i < 128 * 32; i += 256) {   // stage W as float4
    int k = i >> 5, cc = i & 31;
    *(float4*)&wl[k][cc * 4] = *(const float4*)(W + k * NCH + cc * 4);
  }
  for (int i = tid; i < 32 * 32; i += 256) {    // stage 32 rows of x
    int r = i >> 5, cc = i & 31;
    int gr = r0 + r;
    float4 v = make_float4(0.f, 0.f, 0.f, 0.f);
    if (gr < N) v = *(const float4*)(x + gr * NCH + cc * 4);
    *(float4*)&rowL[r][cc * 4] = v;
  }
  __syncthreads();
  int c4 = tid & 31, rg = tid >> 5;   // cols 4*c4..+3, rows 4*rg..+3
  float4 acc[4];
  for (int r = 0; r < 4; r++) acc[r] = make_float4(0.f, 0.f, 0.f, 0.f);
  for (int k = 0; k < 128; k++) {
    float4 w = *(float4*)&wl[k][c4 * 4];
    fma4(acc[0], rowL[rg * 4 + 0][k], w);
    fma4(acc[1], rowL[rg * 4 + 1][k], w);
    fma4(acc[2], rowL[rg * 4 + 2][k], w);
    fma4(acc[3], rowL[rg * 4 + 3][k], w);
  }
  for (int r = 0; r < 4; r++) {
    int gr = r0 + rg * 4 + r;
    if (gr < N) *(float4*)(feat + gr * NCH + c4 * 4) = acc[r];
  }
}

// ---------------- el/er ----------------
__global__ void compute_elr(const float* __restrict__ feat,
                            const float* __restrict__ attn_l,
                            const float* __restrict__ attn_r,
                            float* __restrict__ el, float* __restrict__ er, int N) {
  __shared__ __align__(16) float al[128];
  __shared__ __align__(16) float ar[128];
  if (threadIdx.x < 128) { al[threadIdx.x] = attn_l[threadIdx.x]; ar[threadIdx.x] = attn_r[threadIdx.x]; }
  __syncthreads();
  int i = blockIdx.x * blockDim.x + threadIdx.x;
  if (i >= N * NH) return;
  int n = i >> 3, h = i & 7;
  const float4* f = (const float4*)(feat + n * NCH + h * 16);
  const float4* A = (const float4*)(al + h * 16);
  const float4* B = (const float4*)(ar + h * 16);
  float sl = 0.f, sr = 0.f;
  for (int q = 0; q < 4; q++) {
    float4 fv = f[q], av = A[q], bv = B[q];
    sl += fv.x * av.x + fv.y * av.y + fv.z * av.z + fv.w * av.w;
    sr += fv.x * bv.x + fv.y * bv.y + fv.z * bv.z + fv.w * bv.w;
  }
  el[i] = sl; er[i] = sr;
}

// ---------------- edge pass 1: softmax denominators ----------------
__global__ void edge_denom(const int* __restrict__ src, const int* __restrict__ dst,
                           const float* __restrict__ el, const float* __restrict__ er,
                           float* __restrict__ denom, int E) {
  int i = blockIdx.x * blockDim.x + threadIdx.x;
  if (i >= E * NH) return;
  int e = i >> 3, h = i & 7;
  int s = src[e], d = dst[e];
  float v = el[s * NH + h] + er[d * NH + h];
  v = v > 0.f ? v : SLOPE * v;
  atomicAdd(&denom[d * NH + h], __expf(v));
}

// ---------------- edge pass 2: aggregate messages (1 wave / edge) ----------------
__global__ __launch_bounds__(256) void edge_aggregate(const int* __restrict__ src, const int* __restrict__ dst,
                                                      const float* __restrict__ el, const float* __restrict__ er,
                                                      const float* __restrict__ denom,
                                                      const float* __restrict__ feat,
                                                      float* __restrict__ rst, int E) {
  int wid = (blockIdx.x * 256 + threadIdx.x) >> 6;
  int lane = threadIdx.x & 63;
  if (wid >= E) return;
  int s = src[wid], d = dst[wid];
  float a = 0.f;
  if (lane < NH) {
    float e = el[s * NH + lane] + er[d * NH + lane];
    e = e > 0.f ? e : SLOPE * e;
    a = __expf(e) / denom[d * NH + lane];
  }
  float a0 = __shfl(a, lane >> 4);        // head for col = lane
  float a1 = __shfl(a, 4 + (lane >> 4));  // head for col = lane+64
  float f0 = feat[s * NCH + lane];
  float f1 = feat[s * NCH + 64 + lane];
  atomicAdd(&rst[d * NCH + lane], f0 * a0);
  atomicAdd(&rst[d * NCH + 64 + lane], f1 * a1);
}

// ---------------- BN1 stats over h = x + rst + bias ----------------
// stats layout (floats): sum1 @0 (128*16), sq1 @2048, sum2 @4096, sq2 @6144
__global__ __launch_bounds__(256) void bn1_stats(const float* __restrict__ x, const float* __restrict__ rst,
                                                 const float* __restrict__ bias,
                                                 float* __restrict__ stats, int N) {
  int c = threadIdx.x & 127;
  int rl = threadIdx.x >> 7;  // 0..1
  int r0 = blockIdx.x * 64;
  int rend = r0 + 64; if (rend > N) rend = N;
  float s = 0.f, sq = 0.f;
  float bc = bias[c];
  for (int r = r0 + rl; r < rend; r += 2) {
    float h = x[r * NCH + c] + rst[r * NCH + c] + bc;
    s += h; sq += h * h;
  }
  __shared__ float ps[128], psq[128];
  if (rl == 0) { ps[c] = s; psq[c] = sq; }
  __syncthreads();
  if (rl == 1) { ps[c] += s; psq[c] += sq; }
  __syncthreads();
  if (threadIdx.x < 128) {
    atomicAdd(&stats[threadIdx.x * 16], ps[threadIdx.x]);
    atomicAdd(&stats[2048 + threadIdx.x * 16], psq[threadIdx.x]);
  }
}

// ---------------- finalize mean/rstd ----------------
__global__ void stats_finalize(const float* __restrict__ stats, float* __restrict__ mu,
                               float* __restrict__ rs, int n, int so) {
  int c = threadIdx.x;
  if (c < 128) {
    float s = stats[so + c * 16], sq = stats[so + 2048 + c * 16];
    float m = s / (float)n;
    float v = sq / (float)n - m * m;
    mu[c] = m;
    rs[c] = rsqrtf(v + BN_EPS);
  }
}

// ---------------- BN1 apply: hbn = g*(x+rst+bias - mu)*rs + b ----------------
__global__ void bn1_apply(const float* __restrict__ x, const float* __restrict__ rst,
                          const float* __restrict__ bias,
                          const float* __restrict__ g, const float* __restrict__ b,
                          const float* __restrict__ mu, const float* __restrict__ rs,
                          float* __restrict__ hbn, int total) {
  int i = blockIdx.x * blockDim.x + threadIdx.x;
  if (i >= total) return;
  int c = i & 127;
  float h = x[i] + rst[i] + bias[c];
  hbn[i] = g[c] * (h - mu[c]) * rs[c] + b[c];
}

// ---------------- fused FFN: t = hbn + relu(hbn@W1+b1)@W2 + b2, + BN2 stats ----------------
__global__ __launch_bounds__(256) void ffn_fused(const float* __restrict__ hbn,
                                                 const float* __restrict__ W1, const float* __restrict__ b1,
                                                 const float* __restrict__ W2, const float* __restrict__ b2,
                                                 float* __restrict__ t, float* __restrict__ stats, int N) {
  __shared__ float rowL[32][128];  // 16 KB
  __shared__ float w1c[128][64];   // 32 KB
  __shared__ float w2c[64][128];   // 32 KB
  __shared__ float hid[32][64];    // 8 KB
  __shared__ float csum[128], csq[128];
  int tid = threadIdx.x;
  int r0 = blockIdx.x * 32;
  for (int i = tid; i < 32 * 32; i += 256) {
    int r = i >> 5, cc = i & 31;
    int gr = r0 + r;
    float4 v = make_float4(0.f, 0.f, 0.f, 0.f);
    if (gr < N) v = *(const float4*)(hbn + gr * NCH + cc * 4);
    *(float4*)&rowL[r][cc * 4] = v;
  }
  int c4 = tid & 31, rg2 = tid >> 5;   // fc2/output: cols 4*c4..+3, rows 4*rg2..+3
  int j4 = tid & 15, rg1 = tid >> 4;   // fc1: hidden cols 4*j4..+3, rows 2*rg1..+1
  float4 acc[4];
  {
    float4 bv = *(const float4*)(b2 + c4 * 4);
    for (int r = 0; r < 4; r++) acc[r] = bv;
  }
  for (int ch = 0; ch < 8; ch++) {
    int j0 = ch * 64;
    __syncthreads();  // protect LDS from previous-iteration readers
    for (int i = tid; i < 128 * 16; i += 256) {
      int k = i >> 4, jj = i & 15;
      *(float4*)&w1c[k][jj * 4] = *(const float4*)(W1 + k * HID + j0 + jj * 4);
    }
    for (int i = tid; i < 64 * 32; i += 256) {
      int j = i >> 5, cc = i & 31;
      *(float4*)&w2c[j][cc * 4] = *(const float4*)(W2 + (j0 + j) * NCH + cc * 4);
    }
    __syncthreads();
    // fc1: hidden[r][j] = relu(b1 + sum_k row[r][k]*W1[k][j])
    float4 bv = *(const float4*)(b1 + j0 + j4 * 4);
    float4 h0 = bv, h1 = bv;
    for (int k = 0; k < 128; k++) {
      float4 w = *(float4*)&w1c[k][j4 * 4];
      fma4(h0, rowL[rg1 * 2 + 0][k], w);
      fma4(h1, rowL[rg1 * 2 + 1][k], w);
    }
    h0.x = fmaxf(h0.x, 0.f); h0.y = fmaxf(h0.y, 0.f); h0.z = fmaxf(h0.z, 0.f); h0.w = fmaxf(h0.w, 0.f);
    h1.x = fmaxf(h1.x, 0.f); h1.y = fmaxf(h1.y, 0.f); h1.z = fmaxf(h1.z, 0.f); h1.w = fmaxf(h1.w, 0.f);
    *(float4*)&hid[rg1 * 2 + 0][j4 * 4] = h0;
    *(float4*)&hid[rg1 * 2 + 1][j4 * 4] = h1;
    __syncthreads();
    // fc2: acc += hid @ W2chunk
    for (int j = 0; j < 64; j++) {
      float4 w = *(float4*)&w2c[j][c4 * 4];
      fma4(acc[0], hid[rg2 * 4 + 0][j], w);
      fma4(acc[1], hid[rg2 * 4 + 1][j], w);
      fma4(acc[2], hid[rg2 * 4 + 2][j], w);
      fma4(acc[3], hid[rg2 * 4 + 3][j], w);
    }
  }
  // epilogue: t = row + y, store + BN2 partial stats
  if (tid < 128) { csum[tid] = 0.f; csq[tid] = 0.f; }
  __syncthreads();
  float sx = 0.f, sy = 0.f, sz = 0.f, sw = 0.f;
  float qx = 0.f, qy = 0.f, qz = 0.f, qw = 0.f;
  for (int r = 0; r < 4; r++) {
    int gr = r0 + rg2 * 4 + r;
    if (gr < N) {
      float4 base = *(float4*)&rowL[rg2 * 4 + r][c4 * 4];
      float4 tv = make_float4(base.x + acc[r].x, base.y + acc[r].y,
                              base.z + acc[r].z, base.w + acc[r].w);
      *(float4*)(t + gr * NCH + c4 * 4) = tv;
      sx += tv.x; sy += tv.y; sz += tv.z; sw += tv.w;
      qx += tv.x * tv.x; qy += tv.y * tv.y; qz += tv.z * tv.z; qw += tv.w * tv.w;
    }
  }
  atomicAdd(&csum[c4 * 4 + 0], sx); atomicAdd(&csum[c4 * 4 + 1], sy);
  atomicAdd(&csum[c4 * 4 + 2], sz); atomicAdd(&csum[c4 * 4 + 3], sw);
  atomicAdd(&csq[c4 * 4 + 0], qx); atomicAdd(&csq[c4 * 4 + 1], qy);
  atomicAdd(&csq[c4 * 4 + 2], qz); atomicAdd(&csq[c4 * 4 + 3], qw);
  __syncthreads();
  if (tid < 128) {
    atomicAdd(&stats[4096 + tid * 16], csum[tid]);
    atomicAdd(&stats[6144 + tid * 16], csq[tid]);
  }
}

// ---------------- BN2 apply -> out ----------------
__global__ void bn2_apply(const float* __restrict__ t,
                          const float* __restrict__ g, const float* __restrict__ b,
                          const float* __restrict__ mu, const float* __restrict__ rs,
                          float* __restrict__ out, int total) {
  int i = blockIdx.x * blockDim.x + threadIdx.x;
  if (i >= total) return;
  int c = i & 127;
  out[i] = g[c] * (t[i] - mu[c]) * rs[c] + b[c];
}

extern "C" void kernel_launch(void* const* d_in, const int* in_sizes, int n_in,
                              void* d_out, int out_size, void* d_ws, size_t ws_size,
                              hipStream_t stream) {
  const float* x       = (const float*)d_in[0];
  const int*   src     = (const int*)d_in[1];
  const int*   dst     = (const int*)d_in[2];
  const float* W       = (const float*)d_in[3];
  const float* attn_l  = (const float*)d_in[4];
  const float* attn_r  = (const float*)d_in[5];
  const float* gatb    = (const float*)d_in[6];
  const float* gamma1  = (const float*)d_in[7];
  const float* beta1   = (const float*)d_in[8];
  const float* gamma2  = (const float*)d_in[9];
  const float* beta2   = (const float*)d_in[10];
  const float* W1      = (const float*)d_in[11];
  const float* b1      = (const float*)d_in[12];
  const float* W2      = (const float*)d_in[13];
  const float* b2      = (const float*)d_in[14];
  float* out = (float*)d_out;

  const int N = in_sizes[0] / NCH;   // 50000
  const int E = in_sizes[1];         // 800000

  float* feat  = (float*)d_ws;            // N*128  (reused as hbn)
  float* rst   = feat + (size_t)N * NCH;  // N*128  (reused as t)
  float* el    = rst + (size_t)N * NCH;   // N*8
  float* er    = el + (size_t)N * NH;     // N*8
  float* denom = er + (size_t)N * NH;     // N*8
  float* stats = denom + (size_t)N * NH;  // 4*2048
  float* mus   = stats + 4 * 2048;        // mu1, rs1, mu2, rs2 (128 each)

  // zero rst, denom, stats
  {
    int n4 = N * NCH / 4;
    fill_zero4<<<(n4 + 255) / 256, 256, 0, stream>>>(rst, n4);
    n4 = N * NH / 4;
    fill_zero4<<<(n4 + 255) / 256, 256, 0, stream>>>(denom, n4);
    fill_zero4<<<(4 * 2048 / 4 + 255) / 256, 256, 0, stream>>>(stats, 4 * 2048 / 4);
  }

  int gFeat = (N + 31) / 32;
  feat_gemm<<<gFeat, 256, 0, stream>>>(x, W, feat, N);

  compute_elr<<<(N * NH + 255) / 256, 256, 0, stream>>>(feat, attn_l, attn_r, el, er, N);

  edge_denom<<<(E * NH + 255) / 256, 256, 0, stream>>>(src, dst, el, er, denom, E);

  edge_aggregate<<<(E + 3) / 4, 256, 0, stream>>>(src, dst, el, er, denom, feat, rst, E);

  bn1_stats<<<(N + 63) / 64, 256, 0, stream>>>(x, rst, gatb, stats, N);
  stats_finalize<<<1, 128, 0, stream>>>(stats, mus, mus + 128, N, 0);

  bn1_apply<<<(N * NCH + 255) / 256, 256, 0, stream>>>(x, rst, gatb, gamma1, beta1,
                                                       mus, mus + 128, feat, N * NCH);

  ffn_fused<<<(N + 31) / 32, 256, 0, stream>>>(feat, W1, b1, W2, b2, rst, stats, N);
  stats_finalize<<<1, 128, 0, stream>>>(stats, mus + 256, mus + 384, N, 4096);

  bn2_apply<<<(N * NCH + 255) / 256, 256, 0, stream>>>(rst, gamma2, beta2,
                                                       mus + 256, mus + 384, out, N * NCH);
}

// Round 2
// 665.255 us; speedup vs baseline: 1.4831x; 1.4831x over previous
//
#include <hip/hip_runtime.h>

#define NCH 128   // EMBED
#define NH  8     // HEADS
#define HID 512
#define SLOPE 0.2f
#define BN_EPS 1e-5f
#define LDP 136   // padded LDS inner dim (bf16 units): row stride 272B -> 2-way conflicts only

typedef __attribute__((ext_vector_type(8))) short short8;     // 8 bf16 (4 VGPRs)
typedef __attribute__((ext_vector_type(4))) float floatx4;    // 4 fp32 acc

__device__ inline void fma4(float4& acc, float a, const float4& w) {
  acc.x += a * w.x; acc.y += a * w.y; acc.z += a * w.z; acc.w += a * w.w;
}

__device__ inline unsigned short f2bf(float f) {  // RNE f32 -> bf16 bits
  unsigned u = __float_as_uint(f);
  u += 0x7fffu + ((u >> 16) & 1u);
  return (unsigned short)(u >> 16);
}

// ---------------- zero fill ----------------
__global__ void fill_zero4(float* __restrict__ p, int n4) {
  int i = blockIdx.x * blockDim.x + threadIdx.x;
  if (i < n4) ((float4*)p)[i] = make_float4(0.f, 0.f, 0.f, 0.f);
}

// ---------------- W transposes to bf16 ----------------
__global__ void prep_w1t(const float* __restrict__ W1, unsigned short* __restrict__ W1T) {
  // W1 [128][512] -> W1T [512][128] bf16
  int i = blockIdx.x * 256 + threadIdx.x;   // 65536
  int j = i >> 7, k = i & 127;
  W1T[i] = f2bf(W1[k * HID + j]);
}
__global__ void prep_w2t(const float* __restrict__ W2, unsigned short* __restrict__ W2T) {
  // W2 [512][128] -> W2T [128][512] bf16
  int i = blockIdx.x * 256 + threadIdx.x;   // 65536
  int n = i >> 9, k = i & 511;
  W2T[i] = f2bf(W2[k * NCH + n]);
}

// ---------------- feat = x @ W  (f32, W 128x128 in LDS) ----------------
__global__ __launch_bounds__(256) void feat_gemm(const float* __restrict__ x,
                                                 const float* __restrict__ W,
                                                 float* __restrict__ feat, int N) {
  __shared__ float wl[128][128];
  __shared__ float rowL[32][128];
  int tid = threadIdx.x;
  int r0 = blockIdx.x * 32;
  for (int i = tid; i < 128 * 32; i += 256) {
    int k = i >> 5, cc = i & 31;
    *(float4*)&wl[k][cc * 4] = *(const float4*)(W + k * NCH + cc * 4);
  }
  for (int i = tid; i < 32 * 32; i += 256) {
    int r = i >> 5, cc = i & 31;
    int gr = r0 + r;
    float4 v = make_float4(0.f, 0.f, 0.f, 0.f);
    if (gr < N) v = *(const float4*)(x + gr * NCH + cc * 4);
    *(float4*)&rowL[r][cc * 4] = v;
  }
  __syncthreads();
  int c4 = tid & 31, rg = tid >> 5;
  float4 acc[4];
  for (int r = 0; r < 4; r++) acc[r] = make_float4(0.f, 0.f, 0.f, 0.f);
  for (int k = 0; k < 128; k++) {
    float4 w = *(float4*)&wl[k][c4 * 4];
    fma4(acc[0], rowL[rg * 4 + 0][k], w);
    fma4(acc[1], rowL[rg * 4 + 1][k], w);
    fma4(acc[2], rowL[rg * 4 + 2][k], w);
    fma4(acc[3], rowL[rg * 4 + 3][k], w);
  }
  for (int r = 0; r < 4; r++) {
    int gr = r0 + rg * 4 + r;
    if (gr < N) *(float4*)(feat + gr * NCH + c4 * 4) = acc[r];
  }
}

// ---------------- el/er ----------------
__global__ void compute_elr(const float* __restrict__ feat,
                            const float* __restrict__ attn_l,
                            const float* __restrict__ attn_r,
                            float* __restrict__ el, float* __restrict__ er, int N) {
  __shared__ __align__(16) float al[128];
  __shared__ __align__(16) float ar[128];
  if (threadIdx.x < 128) { al[threadIdx.x] = attn_l[threadIdx.x]; ar[threadIdx.x] = attn_r[threadIdx.x]; }
  __syncthreads();
  int i = blockIdx.x * blockDim.x + threadIdx.x;
  if (i >= N * NH) return;
  int n = i >> 3, h = i & 7;
  const float4* f = (const float4*)(feat + n * NCH + h * 16);
  const float4* A = (const float4*)(al + h * 16);
  const float4* B = (const float4*)(ar + h * 16);
  float sl = 0.f, sr = 0.f;
  for (int q = 0; q < 4; q++) {
    float4 fv = f[q], av = A[q], bv = B[q];
    sl += fv.x * av.x + fv.y * av.y + fv.z * av.z + fv.w * av.w;
    sr += fv.x * bv.x + fv.y * bv.y + fv.z * bv.z + fv.w * bv.w;
  }
  el[i] = sl; er[i] = sr;
}

// ---------------- edge pass 1: softmax denominators ----------------
__global__ void edge_denom(const int* __restrict__ src, const int* __restrict__ dst,
                           const float* __restrict__ el, const float* __restrict__ er,
                           float* __restrict__ denom, int E) {
  int i = blockIdx.x * blockDim.x + threadIdx.x;
  if (i >= E * NH) return;
  int e = i >> 3, h = i & 7;
  int s = src[e], d = dst[e];
  float v = el[s * NH + h] + er[d * NH + h];
  v = v > 0.f ? v : SLOPE * v;
  atomicAdd(&denom[d * NH + h], __expf(v));
}

// ---------------- edge pass 2: aggregate messages (1 wave / edge) ----------------
__global__ __launch_bounds__(256) void edge_aggregate(const int* __restrict__ src, const int* __restrict__ dst,
                                                      const float* __restrict__ el, const float* __restrict__ er,
                                                      const float* __restrict__ denom,
                                                      const float* __restrict__ feat,
                                                      float* __restrict__ rst, int E) {
  int wid = (blockIdx.x * 256 + threadIdx.x) >> 6;
  int lane = threadIdx.x & 63;
  if (wid >= E) return;
  int s = src[wid], d = dst[wid];
  float a = 0.f;
  if (lane < NH) {
    float e = el[s * NH + lane] + er[d * NH + lane];
    e = e > 0.f ? e : SLOPE * e;
    a = __expf(e) / denom[d * NH + lane];
  }
  float a0 = __shfl(a, lane >> 4);
  float a1 = __shfl(a, 4 + (lane >> 4));
  float f0 = feat[s * NCH + lane];
  float f1 = feat[s * NCH + 64 + lane];
  atomicAdd(&rst[d * NCH + lane], f0 * a0);
  atomicAdd(&rst[d * NCH + 64 + lane], f1 * a1);
}

// ---------------- BN1 stats over h = x + rst + bias ----------------
// stats layout (floats): sum1 @0 (128*16), sq1 @2048, sum2 @4096, sq2 @6144
__global__ __launch_bounds__(256) void bn1_stats(const float* __restrict__ x, const float* __restrict__ rst,
                                                 const float* __restrict__ bias,
                                                 float* __restrict__ stats, int N) {
  int c = threadIdx.x & 127;
  int rl = threadIdx.x >> 7;
  int r0 = blockIdx.x * 64;
  int rend = r0 + 64; if (rend > N) rend = N;
  float s = 0.f, sq = 0.f;
  float bc = bias[c];
  for (int r = r0 + rl; r < rend; r += 2) {
    float h = x[r * NCH + c] + rst[r * NCH + c] + bc;
    s += h; sq += h * h;
  }
  __shared__ float ps[128], psq[128];
  if (rl == 0) { ps[c] = s; psq[c] = sq; }
  __syncthreads();
  if (rl == 1) { ps[c] += s; psq[c] += sq; }
  __syncthreads();
  if (threadIdx.x < 128) {
    atomicAdd(&stats[threadIdx.x * 16], ps[threadIdx.x]);
    atomicAdd(&stats[2048 + threadIdx.x * 16], psq[threadIdx.x]);
  }
}

// ---------------- finalize mean/rstd ----------------
__global__ void stats_finalize(const float* __restrict__ stats, float* __restrict__ mu,
                               float* __restrict__ rs, int n, int so) {
  int c = threadIdx.x;
  if (c < 128) {
    float s = stats[so + c * 16], sq = stats[so + 2048 + c * 16];
    float m = s / (float)n;
    float v = sq / (float)n - m * m;
    mu[c] = m;
    rs[c] = rsqrtf(v + BN_EPS);
  }
}

// ---------------- BN1 apply: hbn (f32) + hbnb (bf16) ----------------
__global__ void bn1_apply(const float* __restrict__ x, const float* __restrict__ rst,
                          const float* __restrict__ bias,
                          const float* __restrict__ g, const float* __restrict__ b,
                          const float* __restrict__ mu, const float* __restrict__ rs,
                          float* __restrict__ hbn, unsigned short* __restrict__ hbnb, int total) {
  int i = blockIdx.x * blockDim.x + threadIdx.x;
  if (i >= total) return;
  int c = i & 127;
  float h = x[i] + rst[i] + bias[c];
  float v = g[c] * (h - mu[c]) * rs[c] + b[c];
  hbn[i] = v;
  hbnb[i] = f2bf(v);
}

// ---------------- fused FFN via bf16 MFMA ----------------
// t = hbn + relu(hbn@W1+b1)@W2 + b2, plus BN2 stats.
// block: 512 threads (8 waves), 64 rows; hidden chunked 4 x 128.
__global__ __launch_bounds__(512) void ffn_mfma(const unsigned short* __restrict__ hbnb,
                                                const float* __restrict__ hbn,
                                                const unsigned short* __restrict__ W1T,  // [512][128] bf16
                                                const unsigned short* __restrict__ W2T,  // [128][512] bf16
                                                const float* __restrict__ b1, const float* __restrict__ b2,
                                                float* __restrict__ t, float* __restrict__ stats, int N) {
  __shared__ unsigned short rowA[64 * LDP];   // 17408 B
  __shared__ unsigned short w1t[128 * LDP];   // 34816 B  (w1t[n][k], n in chunk)
  __shared__ unsigned short w2t[128 * LDP];   // 34816 B  (w2t[n][k], k in chunk)
  __shared__ unsigned short hidL[64 * LDP];   // 17408 B
  __shared__ float csum[128], csq[128];
  int tid = threadIdx.x;
  int r0 = blockIdx.x * 64;
  int lane = tid & 63, wid = tid >> 6;
  int quad = lane >> 4, lc = lane & 15;
  int mrow = (wid & 3) * 16;        // wave's row offset within 64
  int chalf = (wid >> 2) * 64;      // wave's 64-col half

  // stage rowA (64x128 bf16): thread: r = tid>>3, 16 bf16 at kg
  {
    int r = tid >> 3, kg = (tid & 7) * 16;
    int gr = r0 + r;
    uint4 z = make_uint4(0, 0, 0, 0);
    uint4 v0 = z, v1 = z;
    if (gr < N) {
      const uint4* gp = (const uint4*)(hbnb + (size_t)gr * NCH + kg);
      v0 = gp[0]; v1 = gp[1];
    }
    *(uint4*)&rowA[r * LDP + kg] = v0;
    *(uint4*)&rowA[r * LDP + kg + 8] = v1;
  }

  floatx4 acc[4];
  for (int tt = 0; tt < 4; tt++) acc[tt] = (floatx4)(0.f);

  for (int ch = 0; ch < 4; ch++) {
    __syncthreads();  // rowA ready (iter0); protect w/hid LDS from prior readers
    // stage w1t, w2t chunk: thread: n = tid>>2, 32 bf16 at kg
    {
      int n = tid >> 2, kg = (tid & 3) * 32;
      const uint4* g1 = (const uint4*)(W1T + ((size_t)(ch * 128 + n)) * 128 + kg);
      const uint4* g2 = (const uint4*)(W2T + (size_t)n * HID + ch * 128 + kg);
      uint4* l1 = (uint4*)&w1t[n * LDP + kg];
      uint4* l2 = (uint4*)&w2t[n * LDP + kg];
      for (int i = 0; i < 4; i++) l1[i] = g1[i];
      for (int i = 0; i < 4; i++) l2[i] = g2[i];
    }
    __syncthreads();

    // fc1: hid(64x128) = rowA(64x128) @ W1chunk(128x128); wave: rows mrow..+15, cols chalf..+63
    floatx4 hacc[4];
    for (int tt = 0; tt < 4; tt++) hacc[tt] = (floatx4)(0.f);
    for (int kk = 0; kk < 4; kk++) {
      short8 a = *(const short8*)&rowA[(mrow + lc) * LDP + kk * 32 + quad * 8];
      for (int tt = 0; tt < 4; tt++) {
        short8 b = *(const short8*)&w1t[(chalf + tt * 16 + lc) * LDP + kk * 32 + quad * 8];
        hacc[tt] = __builtin_amdgcn_mfma_f32_16x16x32_bf16(a, b, hacc[tt], 0, 0, 0);
      }
    }
    // bias + relu -> hidL (bf16)
    for (int tt = 0; tt < 4; tt++) {
      float bv = b1[ch * 128 + chalf + tt * 16 + lc];
      for (int r = 0; r < 4; r++) {
        float v = hacc[tt][r] + bv;
        v = fmaxf(v, 0.f);
        hidL[(mrow + quad * 4 + r) * LDP + chalf + tt * 16 + lc] = f2bf(v);
      }
    }
    __syncthreads();

    // fc2: acc += hid(64x128) @ W2chunk(128x128); wave: rows mrow..+15, out cols chalf..+63
    for (int kk = 0; kk < 4; kk++) {
      short8 a = *(const short8*)&hidL[(mrow + lc) * LDP + kk * 32 + quad * 8];
      for (int tt = 0; tt < 4; tt++) {
        short8 b = *(const short8*)&w2t[(chalf + tt * 16 + lc) * LDP + kk * 32 + quad * 8];
        acc[tt] = __builtin_amdgcn_mfma_f32_16x16x32_bf16(a, b, acc[tt], 0, 0, 0);
      }
    }
  }

  // epilogue: t = hbn + acc + b2, BN2 stats
  if (tid < 128) { csum[tid] = 0.f; csq[tid] = 0.f; }
  __syncthreads();
  for (int tt = 0; tt < 4; tt++) {
    int col = chalf + tt * 16 + lc;
    float b2v = b2[col];
    float s = 0.f, q = 0.f;
    for (int r = 0; r < 4; r++) {
      int grow = r0 + mrow + quad * 4 + r;
      if (grow < N) {
        float base = hbn[(size_t)grow * NCH + col];
        float tv = base + acc[tt][r] + b2v;
        t[(size_t)grow * NCH + col] = tv;
        s += tv; q += tv * tv;
      }
    }
    s += __shfl_xor(s, 16); s += __shfl_xor(s, 32);
    q += __shfl_xor(q, 16); q += __shfl_xor(q, 32);
    if (quad == 0) { atomicAdd(&csum[col], s); atomicAdd(&csq[col], q); }
  }
  __syncthreads();
  if (tid < 128) {
    atomicAdd(&stats[4096 + tid * 16], csum[tid]);
    atomicAdd(&stats[6144 + tid * 16], csq[tid]);
  }
}

// ---------------- BN2 apply -> out ----------------
__global__ void bn2_apply(const float* __restrict__ t,
                          const float* __restrict__ g, const float* __restrict__ b,
                          const float* __restrict__ mu, const float* __restrict__ rs,
                          float* __restrict__ out, int total) {
  int i = blockIdx.x * blockDim.x + threadIdx.x;
  if (i >= total) return;
  int c = i & 127;
  out[i] = g[c] * (t[i] - mu[c]) * rs[c] + b[c];
}

extern "C" void kernel_launch(void* const* d_in, const int* in_sizes, int n_in,
                              void* d_out, int out_size, void* d_ws, size_t ws_size,
                              hipStream_t stream) {
  const float* x       = (const float*)d_in[0];
  const int*   src     = (const int*)d_in[1];
  const int*   dst     = (const int*)d_in[2];
  const float* W       = (const float*)d_in[3];
  const float* attn_l  = (const float*)d_in[4];
  const float* attn_r  = (const float*)d_in[5];
  const float* gatb    = (const float*)d_in[6];
  const float* gamma1  = (const float*)d_in[7];
  const float* beta1   = (const float*)d_in[8];
  const float* gamma2  = (const float*)d_in[9];
  const float* beta2   = (const float*)d_in[10];
  const float* W1      = (const float*)d_in[11];
  const float* b1      = (const float*)d_in[12];
  const float* W2      = (const float*)d_in[13];
  const float* b2      = (const float*)d_in[14];
  float* out = (float*)d_out;

  const int N = in_sizes[0] / NCH;   // 50000
  const int E = in_sizes[1];         // 800000

  float* feat  = (float*)d_ws;            // N*128 (reused as hbn f32)
  float* rst   = feat + (size_t)N * NCH;  // N*128 (reused as t)
  float* el    = rst + (size_t)N * NCH;   // N*8
  float* er    = el + (size_t)N * NH;     // N*8
  float* denom = er + (size_t)N * NH;     // N*8
  float* stats = denom + (size_t)N * NH;  // 4*2048
  float* mus   = stats + 4 * 2048;        // mu1, rs1, mu2, rs2 (128 each)
  unsigned short* hbnb = (unsigned short*)(mus + 512);       // N*128 bf16
  unsigned short* W1T  = hbnb + (size_t)N * NCH;             // 512*128 bf16
  unsigned short* W2T  = W1T + HID * NCH;                    // 128*512 bf16

  // zero rst, denom, stats
  {
    int n4 = N * NCH / 4;
    fill_zero4<<<(n4 + 255) / 256, 256, 0, stream>>>(rst, n4);
    n4 = N * NH / 4;
    fill_zero4<<<(n4 + 255) / 256, 256, 0, stream>>>(denom, n4);
    fill_zero4<<<(4 * 2048 / 4 + 255) / 256, 256, 0, stream>>>(stats, 4 * 2048 / 4);
  }

  prep_w1t<<<HID * NCH / 256, 256, 0, stream>>>(W1, W1T);
  prep_w2t<<<HID * NCH / 256, 256, 0, stream>>>(W2, W2T);

  feat_gemm<<<(N + 31) / 32, 256, 0, stream>>>(x, W, feat, N);

  compute_elr<<<(N * NH + 255) / 256, 256, 0, stream>>>(feat, attn_l, attn_r, el, er, N);

  edge_denom<<<(E * NH + 255) / 256, 256, 0, stream>>>(src, dst, el, er, denom, E);

  edge_aggregate<<<(E + 3) / 4, 256, 0, stream>>>(src, dst, el, er, denom, feat, rst, E);

  bn1_stats<<<(N + 63) / 64, 256, 0, stream>>>(x, rst, gatb, stats, N);
  stats_finalize<<<1, 128, 0, stream>>>(stats, mus, mus + 128, N, 0);

  bn1_apply<<<(N * NCH + 255) / 256, 256, 0, stream>>>(x, rst, gatb, gamma1, beta1,
                                                       mus, mus + 128, feat, hbnb, N * NCH);

  ffn_mfma<<<(N + 63) / 64, 512, 0, stream>>>(hbnb, feat, W1T, W2T, b1, b2, rst, stats, N);
  stats_finalize<<<1, 128, 0, stream>>>(stats, mus + 256, mus + 384, N, 4096);

  bn2_apply<<<(N * NCH + 255) / 256, 256, 0, stream>>>(rst, gamma2, beta2,
                                                       mus + 256, mus + 384, out, N * NCH);
}

// Round 3
// 469.332 us; speedup vs baseline: 2.1022x; 1.4175x over previous
//
#include <hip/hip_runtime.h>

#define NCH 128   // EMBED
#define NH  8     // HEADS
#define HID 512
#define SLOPE 0.2f
#define BN_EPS 1e-5f
#define LDP 136   // padded LDS inner dim (bf16 units)

typedef __attribute__((ext_vector_type(8))) short short8;     // 8 bf16 (4 VGPRs)
typedef __attribute__((ext_vector_type(4))) float floatx4;    // 4 fp32 acc

__device__ inline void fma4(float4& acc, float a, const float4& w) {
  acc.x += a * w.x; acc.y += a * w.y; acc.z += a * w.z; acc.w += a * w.w;
}

__device__ inline unsigned short f2bf(float f) {  // RNE f32 -> bf16 bits
  unsigned u = __float_as_uint(f);
  u += 0x7fffu + ((u >> 16) & 1u);
  return (unsigned short)(u >> 16);
}

// ---------------- zero fill ----------------
__global__ void fill_zero4(float* __restrict__ p, int n4) {
  int i = blockIdx.x * blockDim.x + threadIdx.x;
  if (i < n4) ((float4*)p)[i] = make_float4(0.f, 0.f, 0.f, 0.f);
}

// ---------------- W transposes to bf16 ----------------
__global__ void prep_w1t(const float* __restrict__ W1, unsigned short* __restrict__ W1T) {
  int i = blockIdx.x * 256 + threadIdx.x;   // 65536
  int j = i >> 7, k = i & 127;
  W1T[i] = f2bf(W1[k * HID + j]);
}
__global__ void prep_w2t(const float* __restrict__ W2, unsigned short* __restrict__ W2T) {
  int i = blockIdx.x * 256 + threadIdx.x;   // 65536
  int n = i >> 9, k = i & 511;
  W2T[i] = f2bf(W2[k * NCH + n]);
}

// ---------------- feat = x @ W  (f32, W 128x128 in LDS) ----------------
__global__ __launch_bounds__(256) void feat_gemm(const float* __restrict__ x,
                                                 const float* __restrict__ W,
                                                 float* __restrict__ feat, int N) {
  __shared__ float wl[128][128];
  __shared__ float rowL[32][128];
  int tid = threadIdx.x;
  int r0 = blockIdx.x * 32;
  for (int i = tid; i < 128 * 32; i += 256) {
    int k = i >> 5, cc = i & 31;
    *(float4*)&wl[k][cc * 4] = *(const float4*)(W + k * NCH + cc * 4);
  }
  for (int i = tid; i < 32 * 32; i += 256) {
    int r = i >> 5, cc = i & 31;
    int gr = r0 + r;
    float4 v = make_float4(0.f, 0.f, 0.f, 0.f);
    if (gr < N) v = *(const float4*)(x + gr * NCH + cc * 4);
    *(float4*)&rowL[r][cc * 4] = v;
  }
  __syncthreads();
  int c4 = tid & 31, rg = tid >> 5;
  float4 acc[4];
  for (int r = 0; r < 4; r++) acc[r] = make_float4(0.f, 0.f, 0.f, 0.f);
  for (int k = 0; k < 128; k++) {
    float4 w = *(float4*)&wl[k][c4 * 4];
    fma4(acc[0], rowL[rg * 4 + 0][k], w);
    fma4(acc[1], rowL[rg * 4 + 1][k], w);
    fma4(acc[2], rowL[rg * 4 + 2][k], w);
    fma4(acc[3], rowL[rg * 4 + 3][k], w);
  }
  for (int r = 0; r < 4; r++) {
    int gr = r0 + rg * 4 + r;
    if (gr < N) *(float4*)(feat + gr * NCH + c4 * 4) = acc[r];
  }
}

// ---------------- el/er ----------------
__global__ void compute_elr(const float* __restrict__ feat,
                            const float* __restrict__ attn_l,
                            const float* __restrict__ attn_r,
                            float* __restrict__ el, float* __restrict__ er, int N) {
  __shared__ __align__(16) float al[128];
  __shared__ __align__(16) float ar[128];
  if (threadIdx.x < 128) { al[threadIdx.x] = attn_l[threadIdx.x]; ar[threadIdx.x] = attn_r[threadIdx.x]; }
  __syncthreads();
  int i = blockIdx.x * blockDim.x + threadIdx.x;
  if (i >= N * NH) return;
  int n = i >> 3, h = i & 7;
  const float4* f = (const float4*)(feat + n * NCH + h * 16);
  const float4* A = (const float4*)(al + h * 16);
  const float4* B = (const float4*)(ar + h * 16);
  float sl = 0.f, sr = 0.f;
  for (int q = 0; q < 4; q++) {
    float4 fv = f[q], av = A[q], bv = B[q];
    sl += fv.x * av.x + fv.y * av.y + fv.z * av.z + fv.w * av.w;
    sr += fv.x * bv.x + fv.y * bv.y + fv.z * bv.z + fv.w * bv.w;
  }
  el[i] = sl; er[i] = sr;
}

// ---------------- counting sort of edges by dst ----------------
__global__ void edge_hist(const int* __restrict__ dst, int* __restrict__ cnt, int E) {
  int i = blockIdx.x * 256 + threadIdx.x;
  if (i < E) atomicAdd(&cnt[dst[i]], 1);
}

__global__ void scan_part(const int* __restrict__ cnt, int* __restrict__ off,
                          int* __restrict__ bsum, int N) {
  __shared__ int sh[256];
  int t = threadIdx.x, i = blockIdx.x * 256 + t;
  int v = (i < N) ? cnt[i] : 0;
  sh[t] = v; __syncthreads();
  for (int d = 1; d < 256; d <<= 1) {
    int u = (t >= d) ? sh[t - d] : 0;
    __syncthreads();
    sh[t] += u;
    __syncthreads();
  }
  if (i < N) off[i] = sh[t] - v;           // exclusive within block
  if (t == 255) bsum[blockIdx.x] = sh[255];
}

__global__ void scan_top(int* __restrict__ bsum, int nb) {   // nb <= 256, 1 block
  __shared__ int sh[256];
  int t = threadIdx.x;
  int v = (t < nb) ? bsum[t] : 0;
  sh[t] = v; __syncthreads();
  for (int d = 1; d < 256; d <<= 1) {
    int u = (t >= d) ? sh[t - d] : 0;
    __syncthreads();
    sh[t] += u;
    __syncthreads();
  }
  if (t < nb) bsum[t] = sh[t] - v;         // exclusive block offsets
}

__global__ void scan_add(int* __restrict__ off, const int* __restrict__ bsum,
                         int* __restrict__ cursor, int N) {
  int i = blockIdx.x * 256 + threadIdx.x;
  if (i < N) {
    int v = off[i] + bsum[blockIdx.x];
    off[i] = v;
    cursor[i] = v;
  }
}

__global__ void edge_scatter(const int* __restrict__ src, const int* __restrict__ dst,
                             int* __restrict__ cursor, int* __restrict__ ssrc, int E) {
  int i = blockIdx.x * 256 + threadIdx.x;
  if (i < E) {
    int p = atomicAdd(&cursor[dst[i]], 1);
    ssrc[p] = src[i];
  }
}

// ---------------- gather aggregation: one wave per dst node ----------------
// rst[d] = (sum_e exp(leaky(el[s]+er[d])) * feat[s]) / (sum_e exp(...)), per head.
__global__ __launch_bounds__(256) void gat_gather(const int* __restrict__ ssrc,
                                                  const int* __restrict__ off,
                                                  const int* __restrict__ cnt,
                                                  const float* __restrict__ el,
                                                  const float* __restrict__ er,
                                                  const float* __restrict__ feat,
                                                  float* __restrict__ rst, int N) {
  int node = (blockIdx.x * 256 + threadIdx.x) >> 6;
  int lane = threadIdx.x & 63;
  if (node >= N) return;
  int h0 = lane >> 4;                 // head for channel `lane`; head h0+4 for `lane+64`
  float er0 = er[node * NH + h0];
  float er1 = er[node * NH + h0 + 4];
  int beg = off[node], num = cnt[node];
  float acc0 = 0.f, acc1 = 0.f, den0 = 0.f, den1 = 0.f;
  for (int i = 0; i < num; i++) {
    int s = ssrc[beg + i];
    float e0 = el[s * NH + h0] + er0;      e0 = e0 > 0.f ? e0 : SLOPE * e0;
    float e1 = el[s * NH + h0 + 4] + er1;  e1 = e1 > 0.f ? e1 : SLOPE * e1;
    float w0 = __expf(e0), w1 = __expf(e1);
    acc0 += w0 * feat[(size_t)s * NCH + lane];
    acc1 += w1 * feat[(size_t)s * NCH + 64 + lane];
    den0 += w0; den1 += w1;
  }
  rst[(size_t)node * NCH + lane]      = num ? acc0 / den0 : 0.f;
  rst[(size_t)node * NCH + 64 + lane] = num ? acc1 / den1 : 0.f;
}

// ---------------- BN1 stats over h = x + rst + bias ----------------
// stats layout (floats): sum1 @0 (128*16), sq1 @2048, sum2 @4096, sq2 @6144
__global__ __launch_bounds__(256) void bn1_stats(const float* __restrict__ x, const float* __restrict__ rst,
                                                 const float* __restrict__ bias,
                                                 float* __restrict__ stats, int N) {
  int c = threadIdx.x & 127;
  int rl = threadIdx.x >> 7;
  int r0 = blockIdx.x * 64;
  int rend = r0 + 64; if (rend > N) rend = N;
  float s = 0.f, sq = 0.f;
  float bc = bias[c];
  for (int r = r0 + rl; r < rend; r += 2) {
    float h = x[r * NCH + c] + rst[r * NCH + c] + bc;
    s += h; sq += h * h;
  }
  __shared__ float ps[128], psq[128];
  if (rl == 0) { ps[c] = s; psq[c] = sq; }
  __syncthreads();
  if (rl == 1) { ps[c] += s; psq[c] += sq; }
  __syncthreads();
  if (threadIdx.x < 128) {
    atomicAdd(&stats[threadIdx.x * 16], ps[threadIdx.x]);
    atomicAdd(&stats[2048 + threadIdx.x * 16], psq[threadIdx.x]);
  }
}

// ---------------- finalize mean/rstd ----------------
__global__ void stats_finalize(const float* __restrict__ stats, float* __restrict__ mu,
                               float* __restrict__ rs, int n, int so) {
  int c = threadIdx.x;
  if (c < 128) {
    float s = stats[so + c * 16], sq = stats[so + 2048 + c * 16];
    float m = s / (float)n;
    float v = sq / (float)n - m * m;
    mu[c] = m;
    rs[c] = rsqrtf(v + BN_EPS);
  }
}

// ---------------- BN1 apply: hbn (f32) + hbnb (bf16) ----------------
__global__ void bn1_apply(const float* __restrict__ x, const float* __restrict__ rst,
                          const float* __restrict__ bias,
                          const float* __restrict__ g, const float* __restrict__ b,
                          const float* __restrict__ mu, const float* __restrict__ rs,
                          float* __restrict__ hbn, unsigned short* __restrict__ hbnb, int total) {
  int i = blockIdx.x * blockDim.x + threadIdx.x;
  if (i >= total) return;
  int c = i & 127;
  float h = x[i] + rst[i] + bias[c];
  float v = g[c] * (h - mu[c]) * rs[c] + b[c];
  hbn[i] = v;
  hbnb[i] = f2bf(v);
}

// ---------------- fused FFN via bf16 MFMA ----------------
__global__ __launch_bounds__(512) void ffn_mfma(const unsigned short* __restrict__ hbnb,
                                                const float* __restrict__ hbn,
                                                const unsigned short* __restrict__ W1T,  // [512][128] bf16
                                                const unsigned short* __restrict__ W2T,  // [128][512] bf16
                                                const float* __restrict__ b1, const float* __restrict__ b2,
                                                float* __restrict__ t, float* __restrict__ stats, int N) {
  __shared__ unsigned short rowA[64 * LDP];
  __shared__ unsigned short w1t[128 * LDP];
  __shared__ unsigned short w2t[128 * LDP];
  __shared__ unsigned short hidL[64 * LDP];
  __shared__ float csum[128], csq[128];
  int tid = threadIdx.x;
  int r0 = blockIdx.x * 64;
  int lane = tid & 63, wid = tid >> 6;
  int quad = lane >> 4, lc = lane & 15;
  int mrow = (wid & 3) * 16;
  int chalf = (wid >> 2) * 64;

  {
    int r = tid >> 3, kg = (tid & 7) * 16;
    int gr = r0 + r;
    uint4 z = make_uint4(0, 0, 0, 0);
    uint4 v0 = z, v1 = z;
    if (gr < N) {
      const uint4* gp = (const uint4*)(hbnb + (size_t)gr * NCH + kg);
      v0 = gp[0]; v1 = gp[1];
    }
    *(uint4*)&rowA[r * LDP + kg] = v0;
    *(uint4*)&rowA[r * LDP + kg + 8] = v1;
  }

  floatx4 acc[4];
  for (int tt = 0; tt < 4; tt++) acc[tt] = (floatx4)(0.f);

  for (int ch = 0; ch < 4; ch++) {
    __syncthreads();
    {
      int n = tid >> 2, kg = (tid & 3) * 32;
      const uint4* g1 = (const uint4*)(W1T + ((size_t)(ch * 128 + n)) * 128 + kg);
      const uint4* g2 = (const uint4*)(W2T + (size_t)n * HID + ch * 128 + kg);
      uint4* l1 = (uint4*)&w1t[n * LDP + kg];
      uint4* l2 = (uint4*)&w2t[n * LDP + kg];
      for (int i = 0; i < 4; i++) l1[i] = g1[i];
      for (int i = 0; i < 4; i++) l2[i] = g2[i];
    }
    __syncthreads();

    floatx4 hacc[4];
    for (int tt = 0; tt < 4; tt++) hacc[tt] = (floatx4)(0.f);
    for (int kk = 0; kk < 4; kk++) {
      short8 a = *(const short8*)&rowA[(mrow + lc) * LDP + kk * 32 + quad * 8];
      for (int tt = 0; tt < 4; tt++) {
        short8 b = *(const short8*)&w1t[(chalf + tt * 16 + lc) * LDP + kk * 32 + quad * 8];
        hacc[tt] = __builtin_amdgcn_mfma_f32_16x16x32_bf16(a, b, hacc[tt], 0, 0, 0);
      }
    }
    for (int tt = 0; tt < 4; tt++) {
      float bv = b1[ch * 128 + chalf + tt * 16 + lc];
      for (int r = 0; r < 4; r++) {
        float v = hacc[tt][r] + bv;
        v = fmaxf(v, 0.f);
        hidL[(mrow + quad * 4 + r) * LDP + chalf + tt * 16 + lc] = f2bf(v);
      }
    }
    __syncthreads();

    for (int kk = 0; kk < 4; kk++) {
      short8 a = *(const short8*)&hidL[(mrow + lc) * LDP + kk * 32 + quad * 8];
      for (int tt = 0; tt < 4; tt++) {
        short8 b = *(const short8*)&w2t[(chalf + tt * 16 + lc) * LDP + kk * 32 + quad * 8];
        acc[tt] = __builtin_amdgcn_mfma_f32_16x16x32_bf16(a, b, acc[tt], 0, 0, 0);
      }
    }
  }

  if (tid < 128) { csum[tid] = 0.f; csq[tid] = 0.f; }
  __syncthreads();
  for (int tt = 0; tt < 4; tt++) {
    int col = chalf + tt * 16 + lc;
    float b2v = b2[col];
    float s = 0.f, q = 0.f;
    for (int r = 0; r < 4; r++) {
      int grow = r0 + mrow + quad * 4 + r;
      if (grow < N) {
        float base = hbn[(size_t)grow * NCH + col];
        float tv = base + acc[tt][r] + b2v;
        t[(size_t)grow * NCH + col] = tv;
        s += tv; q += tv * tv;
      }
    }
    s += __shfl_xor(s, 16); s += __shfl_xor(s, 32);
    q += __shfl_xor(q, 16); q += __shfl_xor(q, 32);
    if (quad == 0) { atomicAdd(&csum[col], s); atomicAdd(&csq[col], q); }
  }
  __syncthreads();
  if (tid < 128) {
    atomicAdd(&stats[4096 + tid * 16], csum[tid]);
    atomicAdd(&stats[6144 + tid * 16], csq[tid]);
  }
}

// ---------------- BN2 apply -> out ----------------
__global__ void bn2_apply(const float* __restrict__ t,
                          const float* __restrict__ g, const float* __restrict__ b,
                          const float* __restrict__ mu, const float* __restrict__ rs,
                          float* __restrict__ out, int total) {
  int i = blockIdx.x * blockDim.x + threadIdx.x;
  if (i >= total) return;
  int c = i & 127;
  out[i] = g[c] * (t[i] - mu[c]) * rs[c] + b[c];
}

extern "C" void kernel_launch(void* const* d_in, const int* in_sizes, int n_in,
                              void* d_out, int out_size, void* d_ws, size_t ws_size,
                              hipStream_t stream) {
  const float* x       = (const float*)d_in[0];
  const int*   src     = (const int*)d_in[1];
  const int*   dst     = (const int*)d_in[2];
  const float* W       = (const float*)d_in[3];
  const float* attn_l  = (const float*)d_in[4];
  const float* attn_r  = (const float*)d_in[5];
  const float* gatb    = (const float*)d_in[6];
  const float* gamma1  = (const float*)d_in[7];
  const float* beta1   = (const float*)d_in[8];
  const float* gamma2  = (const float*)d_in[9];
  const float* beta2   = (const float*)d_in[10];
  const float* W1      = (const float*)d_in[11];
  const float* b1      = (const float*)d_in[12];
  const float* W2      = (const float*)d_in[13];
  const float* b2      = (const float*)d_in[14];
  float* out = (float*)d_out;

  const int N = in_sizes[0] / NCH;   // 50000
  const int E = in_sizes[1];         // 800000
  const int nb = (N + 255) / 256;    // 196 scan blocks

  float* feat  = (float*)d_ws;            // N*128 (reused as hbn f32)
  float* rst   = feat + (size_t)N * NCH;  // N*128 (reused as t)
  float* el    = rst + (size_t)N * NCH;   // N*8
  float* er    = el + (size_t)N * NH;     // N*8
  float* stats = er + (size_t)N * NH;     // 8192
  float* mus   = stats + 4 * 2048;        // 512
  unsigned short* hbnb = (unsigned short*)(mus + 512);   // N*128 bf16
  unsigned short* W1T  = hbnb + (size_t)N * NCH;         // 512*128 bf16
  unsigned short* W2T  = W1T + HID * NCH;                // 128*512 bf16
  int* cnt    = (int*)(W2T + HID * NCH);                 // N
  int* off    = cnt + N;                                 // N
  int* cursor = off + N;                                 // N
  int* bsum   = cursor + N;                              // 256
  int* ssrc   = bsum + 256;                              // E

  fill_zero4<<<(2048 + 255) / 256, 256, 0, stream>>>(stats, 2048);
  fill_zero4<<<(N / 4 + 255) / 256, 256, 0, stream>>>((float*)cnt, N / 4);

  prep_w1t<<<HID * NCH / 256, 256, 0, stream>>>(W1, W1T);
  prep_w2t<<<HID * NCH / 256, 256, 0, stream>>>(W2, W2T);

  feat_gemm<<<(N + 31) / 32, 256, 0, stream>>>(x, W, feat, N);
  compute_elr<<<(N * NH + 255) / 256, 256, 0, stream>>>(feat, attn_l, attn_r, el, er, N);

  edge_hist<<<(E + 255) / 256, 256, 0, stream>>>(dst, cnt, E);
  scan_part<<<nb, 256, 0, stream>>>(cnt, off, bsum, N);
  scan_top<<<1, 256, 0, stream>>>(bsum, nb);
  scan_add<<<nb, 256, 0, stream>>>(off, bsum, cursor, N);
  edge_scatter<<<(E + 255) / 256, 256, 0, stream>>>(src, dst, cursor, ssrc, E);

  gat_gather<<<(N * 64 + 255) / 256, 256, 0, stream>>>(ssrc, off, cnt, el, er, feat, rst, N);

  bn1_stats<<<(N + 63) / 64, 256, 0, stream>>>(x, rst, gatb, stats, N);
  stats_finalize<<<1, 128, 0, stream>>>(stats, mus, mus + 128, N, 0);

  bn1_apply<<<(N * NCH + 255) / 256, 256, 0, stream>>>(x, rst, gatb, gamma1, beta1,
                                                       mus, mus + 128, feat, hbnb, N * NCH);

  ffn_mfma<<<(N + 63) / 64, 512, 0, stream>>>(hbnb, feat, W1T, W2T, b1, b2, rst, stats, N);
  stats_finalize<<<1, 128, 0, stream>>>(stats, mus + 256, mus + 384, N, 4096);

  bn2_apply<<<(N * NCH + 255) / 256, 256, 0, stream>>>(rst, gamma2, beta2,
                                                       mus + 256, mus + 384, out, N * NCH);
}